// Round 1
// baseline (1560.263 us; speedup 1.0000x reference)
//
#include <hip/hip_runtime.h>

#define NN 100000
#define EE 1000000
#define IN_F 128
#define HID_F 64
#define OUT_F 40

static __device__ __forceinline__ void atomic_add_f32(float* p, float v) {
    __hip_atomic_fetch_add(p, v, __ATOMIC_RELAXED, __HIP_MEMORY_SCOPE_AGENT);
}

__global__ __launch_bounds__(256) void k_deg_init(float* deg) {
    int i = blockIdx.x * 256 + threadIdx.x;
    if (i < NN) deg[i] = 1.0f;  // self-loop
}

__global__ __launch_bounds__(256) void k_deg_count(const int* __restrict__ ei, float* deg) {
    int e = blockIdx.x * 256 + threadIdx.x;
    if (e < EE) atomic_add_f32(&deg[ei[EE + e]], 1.0f);
}

__global__ __launch_bounds__(256) void k_dinv(float* deg) {
    int i = blockIdx.x * 256 + threadIdx.x;
    if (i < NN) deg[i] = rsqrtf(deg[i]);  // deg >= 1 always (self-loop)
}

// h1 = x @ W1 ; agg1 = h1 * dinv^2 (self-loop init)
// block: 256 threads = 16 rows x 16 feature-groups (4 feats each)
__global__ __launch_bounds__(256) void k_gemm1(const float* __restrict__ x,
                                               const float* __restrict__ W1,
                                               const float* __restrict__ dinv,
                                               float* __restrict__ h1,
                                               float* __restrict__ agg1) {
    __shared__ float ws[IN_F * HID_F];   // 32 KB
    __shared__ float xs[16 * 132];       // 16 rows padded to 132 (bank spread)
    const int tid = threadIdx.x;
    const int r0 = blockIdx.x * 16;

    for (int i = tid * 4; i < IN_F * HID_F; i += 256 * 4)
        *(float4*)&ws[i] = *(const float4*)&W1[i];
    for (int i = tid * 4; i < 16 * IN_F; i += 256 * 4) {
        int r = i >> 7, k = i & 127;
        *(float4*)&xs[r * 132 + k] = *(const float4*)&x[(size_t)(r0 + r) * IN_F + k];
    }
    __syncthreads();

    const int fg = tid & 15;   // feature group -> features fg*4 .. fg*4+3
    const int rl = tid >> 4;   // local row
    float4 acc = {0.f, 0.f, 0.f, 0.f};
    #pragma unroll
    for (int kk = 0; kk < 32; ++kk) {
        float4 xv = *(float4*)&xs[rl * 132 + kk * 4];
        float xj;
        float4 wv;
        wv = *(float4*)&ws[(kk * 4 + 0) * HID_F + fg * 4]; xj = xv.x;
        acc.x += xj * wv.x; acc.y += xj * wv.y; acc.z += xj * wv.z; acc.w += xj * wv.w;
        wv = *(float4*)&ws[(kk * 4 + 1) * HID_F + fg * 4]; xj = xv.y;
        acc.x += xj * wv.x; acc.y += xj * wv.y; acc.z += xj * wv.z; acc.w += xj * wv.w;
        wv = *(float4*)&ws[(kk * 4 + 2) * HID_F + fg * 4]; xj = xv.z;
        acc.x += xj * wv.x; acc.y += xj * wv.y; acc.z += xj * wv.z; acc.w += xj * wv.w;
        wv = *(float4*)&ws[(kk * 4 + 3) * HID_F + fg * 4]; xj = xv.w;
        acc.x += xj * wv.x; acc.y += xj * wv.y; acc.z += xj * wv.z; acc.w += xj * wv.w;
    }
    const int row = r0 + rl;
    const float dv = dinv[row];
    const float d2 = dv * dv;
    *(float4*)&h1[(size_t)row * HID_F + fg * 4] = acc;
    float4 a2 = {acc.x * d2, acc.y * d2, acc.z * d2, acc.w * d2};
    *(float4*)&agg1[(size_t)row * HID_F + fg * 4] = a2;
}

// agg1[dst] += h1[src] * dinv[src]*dinv[dst]   (16 threads per edge)
__global__ __launch_bounds__(256) void k_scatter1(const int* __restrict__ ei,
                                                  const float* __restrict__ dinv,
                                                  const float* __restrict__ h1,
                                                  float* __restrict__ agg1) {
    int idx = blockIdx.x * 256 + threadIdx.x;   // E*16 = 16M total
    int e = idx >> 4;
    int g = idx & 15;
    int s = ei[e];
    int d = ei[EE + e];
    float w = dinv[s] * dinv[d];
    float4 v = *(const float4*)&h1[(size_t)s * HID_F + g * 4];
    float* a = &agg1[(size_t)d * HID_F + g * 4];
    atomic_add_f32(a + 0, v.x * w);
    atomic_add_f32(a + 1, v.y * w);
    atomic_add_f32(a + 2, v.z * w);
    atomic_add_f32(a + 3, v.w * w);
}

// h = relu(agg1 + b1); h2 = h @ W2; out = h2*dinv^2 + b2 (self-loop + bias init)
// block: 320 threads = 32 rows x 10 feature-groups (4 feats each)
__global__ __launch_bounds__(320) void k_gemm2(const float* __restrict__ agg1,
                                               const float* __restrict__ b1,
                                               const float* __restrict__ W2,
                                               const float* __restrict__ b2,
                                               const float* __restrict__ dinv,
                                               float* __restrict__ h2,
                                               float* __restrict__ out) {
    __shared__ float w2s[HID_F * OUT_F];  // 2560 floats
    __shared__ float hs[32 * 68];         // 32 rows padded to 68
    const int tid = threadIdx.x;
    const int r0 = blockIdx.x * 32;

    for (int i = tid * 4; i < HID_F * OUT_F; i += 320 * 4)
        *(float4*)&w2s[i] = *(const float4*)&W2[i];
    for (int i = tid; i < 32 * HID_F; i += 320) {
        int r = i >> 6, k = i & 63;
        float v = agg1[(size_t)(r0 + r) * HID_F + k] + b1[k];
        hs[r * 68 + k] = fmaxf(v, 0.f);
    }
    __syncthreads();

    const int t = tid % 10;   // feature group -> features t*4 .. t*4+3
    const int rl = tid / 10;  // local row 0..31
    float4 acc = {0.f, 0.f, 0.f, 0.f};
    #pragma unroll 8
    for (int k = 0; k < HID_F; ++k) {
        float xv = hs[rl * 68 + k];
        float4 wv = *(float4*)&w2s[k * OUT_F + t * 4];
        acc.x += xv * wv.x; acc.y += xv * wv.y; acc.z += xv * wv.z; acc.w += xv * wv.w;
    }
    const int row = r0 + rl;
    const float dv = dinv[row];
    const float d2 = dv * dv;
    *(float4*)&h2[(size_t)row * OUT_F + t * 4] = acc;
    float4 bv = *(const float4*)&b2[t * 4];
    float4 o = {acc.x * d2 + bv.x, acc.y * d2 + bv.y, acc.z * d2 + bv.z, acc.w * d2 + bv.w};
    *(float4*)&out[(size_t)row * OUT_F + t * 4] = o;
}

// out[dst] += h2[src] * dinv[src]*dinv[dst]   (10 threads per edge)
__global__ __launch_bounds__(320) void k_scatter2(const int* __restrict__ ei,
                                                  const float* __restrict__ dinv,
                                                  const float* __restrict__ h2,
                                                  float* __restrict__ out) {
    int idx = blockIdx.x * 320 + threadIdx.x;   // E*10 = 10M total
    int e = idx / 10;
    int t = idx % 10;
    int s = ei[e];
    int d = ei[EE + e];
    float w = dinv[s] * dinv[d];
    float4 v = *(const float4*)&h2[(size_t)s * OUT_F + t * 4];
    float* a = &out[(size_t)d * OUT_F + t * 4];
    atomic_add_f32(a + 0, v.x * w);
    atomic_add_f32(a + 1, v.y * w);
    atomic_add_f32(a + 2, v.z * w);
    atomic_add_f32(a + 3, v.w * w);
}

extern "C" void kernel_launch(void* const* d_in, const int* in_sizes, int n_in,
                              void* d_out, int out_size, void* d_ws, size_t ws_size,
                              hipStream_t stream) {
    const float* x  = (const float*)d_in[0];
    const int*   ei = (const int*)d_in[1];
    const float* W1 = (const float*)d_in[2];
    const float* b1 = (const float*)d_in[3];
    const float* W2 = (const float*)d_in[4];
    const float* b2 = (const float*)d_in[5];
    float* out = (float*)d_out;

    float* ws   = (float*)d_ws;
    float* dinv = ws;                         // NN
    float* h1   = dinv + NN;                  // NN*64
    float* agg1 = h1 + (size_t)NN * HID_F;    // NN*64
    float* h2   = agg1 + (size_t)NN * HID_F;  // NN*40

    k_deg_init <<<(NN + 255) / 256, 256, 0, stream>>>(dinv);
    k_deg_count<<<(EE + 255) / 256, 256, 0, stream>>>(ei, dinv);
    k_dinv     <<<(NN + 255) / 256, 256, 0, stream>>>(dinv);
    k_gemm1    <<<NN / 16, 256, 0, stream>>>(x, W1, dinv, h1, agg1);
    k_scatter1 <<<(EE * 16) / 256, 256, 0, stream>>>(ei, dinv, h1, agg1);
    k_gemm2    <<<NN / 32, 320, 0, stream>>>(agg1, b1, W2, b2, dinv, h2, out);
    k_scatter2 <<<(EE * 10) / 320, 320, 0, stream>>>(ei, dinv, h2, out);
}

// Round 2
// 304.087 us; speedup vs baseline: 5.1310x; 5.1310x over previous
//
#include <hip/hip_runtime.h>

#define NN 100000
#define EE 1000000
#define IN_F 128
#define HID_F 64
#define OUT_F 40
#define NB1 98   // ceil(NN/1024) for scan

static __device__ __forceinline__ int atomic_add_i32(int* p, int v) {
    return __hip_atomic_fetch_add(p, v, __ATOMIC_RELAXED, __HIP_MEMORY_SCOPE_AGENT);
}

__global__ __launch_bounds__(256) void k_zero(int* deg, int* cursor) {
    int i = blockIdx.x * 256 + threadIdx.x;
    if (i < NN) { deg[i] = 0; cursor[i] = 0; }
}

__global__ __launch_bounds__(256) void k_deg_count(const int* __restrict__ ei, int* deg) {
    int e = blockIdx.x * 256 + threadIdx.x;
    if (e < EE) atomic_add_i32(&deg[ei[EE + e]], 1);
}

__global__ __launch_bounds__(256) void k_dinv(const int* __restrict__ deg, float* dinv) {
    int i = blockIdx.x * 256 + threadIdx.x;
    if (i < NN) dinv[i] = rsqrtf((float)(deg[i] + 1));  // +1 self-loop
}

// exclusive scan, phase 1: per-block (1024 elems) partial scan + block sums
__global__ __launch_bounds__(256) void k_scan1(const int* __restrict__ deg,
                                               int* __restrict__ rp, int* __restrict__ bsum) {
    __shared__ int sh[256];
    const int t = threadIdx.x;
    const int base = blockIdx.x * 1024 + t * 4;
    int v0 = (base + 0 < NN) ? deg[base + 0] : 0;
    int v1 = (base + 1 < NN) ? deg[base + 1] : 0;
    int v2 = (base + 2 < NN) ? deg[base + 2] : 0;
    int v3 = (base + 3 < NN) ? deg[base + 3] : 0;
    int s = v0 + v1 + v2 + v3;
    sh[t] = s;
    __syncthreads();
    for (int off = 1; off < 256; off <<= 1) {
        int x = (t >= off) ? sh[t - off] : 0;
        __syncthreads();
        sh[t] += x;
        __syncthreads();
    }
    int excl = sh[t] - s;
    if (t == 255) bsum[blockIdx.x] = sh[255];
    if (base + 0 < NN) rp[base + 0] = excl;
    if (base + 1 < NN) rp[base + 1] = excl + v0;
    if (base + 2 < NN) rp[base + 2] = excl + v0 + v1;
    if (base + 3 < NN) rp[base + 3] = excl + v0 + v1 + v2;
}

// phase 2: single-block exclusive scan of block sums
__global__ __launch_bounds__(128) void k_scan2(int* __restrict__ bsum, int* __restrict__ boff) {
    __shared__ int sh[128];
    const int t = threadIdx.x;
    int v = (t < NB1) ? bsum[t] : 0;
    sh[t] = v;
    __syncthreads();
    for (int off = 1; off < 128; off <<= 1) {
        int x = (t >= off) ? sh[t - off] : 0;
        __syncthreads();
        sh[t] += x;
        __syncthreads();
    }
    if (t < NB1) boff[t] = sh[t] - v;
}

// phase 3: add block offsets
__global__ __launch_bounds__(256) void k_scan3(int* __restrict__ rp, const int* __restrict__ boff) {
    int i = blockIdx.x * 256 + threadIdx.x;
    if (i < NN) rp[i] += boff[i >> 10];
}

// CSR fill: csr[pos] = {src, w}
__global__ __launch_bounds__(256) void k_fill(const int* __restrict__ ei,
                                              const float* __restrict__ dinv,
                                              const int* __restrict__ rp,
                                              int* __restrict__ cursor,
                                              int2* __restrict__ csr) {
    int e = blockIdx.x * 256 + threadIdx.x;
    if (e >= EE) return;
    int s = ei[e];
    int d = ei[EE + e];
    float w = dinv[s] * dinv[d];
    int pos = rp[d] + atomic_add_i32(&cursor[d], 1);
    csr[pos] = make_int2(s, __float_as_int(w));
}

// h1 = x @ W1
__global__ __launch_bounds__(256) void k_gemm1(const float* __restrict__ x,
                                               const float* __restrict__ W1,
                                               float* __restrict__ h1) {
    __shared__ float ws[IN_F * HID_F];   // 32 KB
    __shared__ float xs[16 * 132];
    const int tid = threadIdx.x;
    const int r0 = blockIdx.x * 16;

    for (int i = tid * 4; i < IN_F * HID_F; i += 256 * 4)
        *(float4*)&ws[i] = *(const float4*)&W1[i];
    for (int i = tid * 4; i < 16 * IN_F; i += 256 * 4) {
        int r = i >> 7, k = i & 127;
        *(float4*)&xs[r * 132 + k] = *(const float4*)&x[(size_t)(r0 + r) * IN_F + k];
    }
    __syncthreads();

    const int fg = tid & 15;
    const int rl = tid >> 4;
    float4 acc = {0.f, 0.f, 0.f, 0.f};
    #pragma unroll
    for (int kk = 0; kk < 32; ++kk) {
        float4 xv = *(float4*)&xs[rl * 132 + kk * 4];
        float xj;
        float4 wv;
        wv = *(float4*)&ws[(kk * 4 + 0) * HID_F + fg * 4]; xj = xv.x;
        acc.x += xj * wv.x; acc.y += xj * wv.y; acc.z += xj * wv.z; acc.w += xj * wv.w;
        wv = *(float4*)&ws[(kk * 4 + 1) * HID_F + fg * 4]; xj = xv.y;
        acc.x += xj * wv.x; acc.y += xj * wv.y; acc.z += xj * wv.z; acc.w += xj * wv.w;
        wv = *(float4*)&ws[(kk * 4 + 2) * HID_F + fg * 4]; xj = xv.z;
        acc.x += xj * wv.x; acc.y += xj * wv.y; acc.z += xj * wv.z; acc.w += xj * wv.w;
        wv = *(float4*)&ws[(kk * 4 + 3) * HID_F + fg * 4]; xj = xv.w;
        acc.x += xj * wv.x; acc.y += xj * wv.y; acc.z += xj * wv.z; acc.w += xj * wv.w;
    }
    *(float4*)&h1[(size_t)(r0 + rl) * HID_F + fg * 4] = acc;
}

// agg1: one wave per node, lane = feature (64)
// h_relu[v] = relu( h1[v]*dinv^2 + sum_e w*h1[src] + b1 )
__global__ __launch_bounds__(256) void k_agg1(const float* __restrict__ h1,
                                              const float* __restrict__ dinv,
                                              const int* __restrict__ rp,
                                              const int* __restrict__ deg,
                                              const int2* __restrict__ csr,
                                              const float* __restrict__ b1,
                                              float* __restrict__ h_relu) {
    const int v = blockIdx.x * 4 + (threadIdx.x >> 6);
    const int lane = threadIdx.x & 63;
    if (v >= NN) return;
    const float dv = dinv[v];
    float acc = h1[(v << 6) | lane] * dv * dv;
    int e = rp[v];
    const int end = e + deg[v];
    for (; e + 1 < end; e += 2) {
        int2 p0 = csr[e];
        int2 p1 = csr[e + 1];
        float x0 = h1[(p0.x << 6) | lane];
        float x1 = h1[(p1.x << 6) | lane];
        acc += __int_as_float(p0.y) * x0;
        acc += __int_as_float(p1.y) * x1;
    }
    if (e < end) {
        int2 p = csr[e];
        acc += __int_as_float(p.y) * h1[(p.x << 6) | lane];
    }
    h_relu[(v << 6) | lane] = fmaxf(acc + b1[lane], 0.f);
}

// h2 = h_relu @ W2
__global__ __launch_bounds__(320) void k_gemm2(const float* __restrict__ hr,
                                               const float* __restrict__ W2,
                                               float* __restrict__ h2) {
    __shared__ float w2s[HID_F * OUT_F];
    __shared__ float hs[32 * 68];
    const int tid = threadIdx.x;
    const int r0 = blockIdx.x * 32;

    for (int i = tid * 4; i < HID_F * OUT_F; i += 320 * 4)
        *(float4*)&w2s[i] = *(const float4*)&W2[i];
    for (int i = tid * 4; i < 32 * HID_F; i += 320 * 4) {
        int r = i >> 6, k = i & 63;
        *(float4*)&hs[r * 68 + k] = *(const float4*)&hr[(size_t)(r0 + r) * HID_F + k];
    }
    __syncthreads();

    const int t = tid % 10;
    const int rl = tid / 10;
    float4 acc = {0.f, 0.f, 0.f, 0.f};
    #pragma unroll 8
    for (int k = 0; k < HID_F; ++k) {
        float xv = hs[rl * 68 + k];
        float4 wv = *(float4*)&w2s[k * OUT_F + t * 4];
        acc.x += xv * wv.x; acc.y += xv * wv.y; acc.z += xv * wv.z; acc.w += xv * wv.w;
    }
    *(float4*)&h2[(size_t)(r0 + rl) * OUT_F + t * 4] = acc;
}

// agg2: one wave per node, lanes 0..39 = features
// out[v] = h2[v]*dinv^2 + sum_e w*h2[src] + b2
__global__ __launch_bounds__(256) void k_agg2(const float* __restrict__ h2,
                                              const float* __restrict__ dinv,
                                              const int* __restrict__ rp,
                                              const int* __restrict__ deg,
                                              const int2* __restrict__ csr,
                                              const float* __restrict__ b2,
                                              float* __restrict__ out) {
    const int v = blockIdx.x * 4 + (threadIdx.x >> 6);
    const int lane = threadIdx.x & 63;
    if (v >= NN || lane >= OUT_F) return;
    const float dv = dinv[v];
    float acc = h2[v * OUT_F + lane] * dv * dv;
    int e = rp[v];
    const int end = e + deg[v];
    for (; e + 1 < end; e += 2) {
        int2 p0 = csr[e];
        int2 p1 = csr[e + 1];
        float x0 = h2[p0.x * OUT_F + lane];
        float x1 = h2[p1.x * OUT_F + lane];
        acc += __int_as_float(p0.y) * x0;
        acc += __int_as_float(p1.y) * x1;
    }
    if (e < end) {
        int2 p = csr[e];
        acc += __int_as_float(p.y) * h2[p.x * OUT_F + lane];
    }
    out[v * OUT_F + lane] = acc + b2[lane];
}

extern "C" void kernel_launch(void* const* d_in, const int* in_sizes, int n_in,
                              void* d_out, int out_size, void* d_ws, size_t ws_size,
                              hipStream_t stream) {
    const float* x  = (const float*)d_in[0];
    const int*   ei = (const int*)d_in[1];
    const float* W1 = (const float*)d_in[2];
    const float* b1 = (const float*)d_in[3];
    const float* W2 = (const float*)d_in[4];
    const float* b2 = (const float*)d_in[5];
    float* out = (float*)d_out;

    char* p = (char*)d_ws;
    float* dinv  = (float*)p;                 p += (size_t)NN * 4;
    int*   deg   = (int*)p;                   p += (size_t)NN * 4;
    int*   rp    = (int*)p;                   p += (size_t)NN * 4;
    int*   cursor= (int*)p;                   p += (size_t)NN * 4;
    int*   bsum  = (int*)p;                   p += 128 * 4;
    int*   boff  = (int*)p;                   p += 128 * 4;
    int2*  csr   = (int2*)p;                  p += (size_t)EE * 8;
    float* h1    = (float*)p;                 p += (size_t)NN * HID_F * 4;  // reused as h2
    float* hrelu = (float*)p;                 p += (size_t)NN * HID_F * 4;
    float* h2    = h1;  // h1 dead after agg1

    k_zero     <<<(NN + 255) / 256, 256, 0, stream>>>(deg, cursor);
    k_deg_count<<<(EE + 255) / 256, 256, 0, stream>>>(ei, deg);
    k_dinv     <<<(NN + 255) / 256, 256, 0, stream>>>(deg, dinv);
    k_scan1    <<<NB1, 256, 0, stream>>>(deg, rp, bsum);
    k_scan2    <<<1, 128, 0, stream>>>(bsum, boff);
    k_scan3    <<<(NN + 255) / 256, 256, 0, stream>>>(rp, boff);
    k_fill     <<<(EE + 255) / 256, 256, 0, stream>>>(ei, dinv, rp, cursor, csr);
    k_gemm1    <<<NN / 16, 256, 0, stream>>>(x, W1, h1);
    k_agg1     <<<(NN + 3) / 4, 256, 0, stream>>>(h1, dinv, rp, deg, csr, b1, hrelu);
    k_gemm2    <<<NN / 32, 320, 0, stream>>>(hrelu, W2, h2);
    k_agg2     <<<(NN + 3) / 4, 256, 0, stream>>>(h2, dinv, rp, deg, csr, b2, out);
}

// Round 3
// 232.448 us; speedup vs baseline: 6.7123x; 1.3082x over previous
//
#include <hip/hip_runtime.h>

#define NN 100000
#define EE 1000000
#define IN_F 128
#define HID_F 64
#define OUT_F 40
#define NB1 98   // ceil(NN/1024) for scan

typedef _Float16 half8 __attribute__((ext_vector_type(8)));
typedef float f32x4 __attribute__((ext_vector_type(4)));

#define SWZ(b, row) ((b) ^ (((row) & 7) << 4))

static __device__ __forceinline__ int atomic_add_i32(int* p, int v) {
    return __hip_atomic_fetch_add(p, v, __ATOMIC_RELAXED, __HIP_MEMORY_SCOPE_AGENT);
}

static __device__ __forceinline__ float2 unpack_h2(unsigned u) {
    union { unsigned u; _Float16 h[2]; } cv; cv.u = u;
    return make_float2((float)cv.h[0], (float)cv.h[1]);
}

// W1 [128][64] -> w1t fp16 [64][128]; W2 [64][40] -> w2t fp16 [48 pad][64]
__global__ __launch_bounds__(256) void k_prep(const float* __restrict__ W1,
                                              const float* __restrict__ W2,
                                              _Float16* __restrict__ w1t,
                                              _Float16* __restrict__ w2t) {
    int i = blockIdx.x * 256 + threadIdx.x;
    if (i < IN_F * HID_F) {
        int k = i >> 6, n = i & 63;
        w1t[n * IN_F + k] = (_Float16)W1[i];
    }
    int j = i - IN_F * HID_F;
    if (j >= 0 && j < 48 * HID_F) {
        int n = j >> 6, k = j & 63;
        w2t[j] = (_Float16)((n < OUT_F) ? W2[k * OUT_F + n] : 0.f);
    }
}

__global__ __launch_bounds__(256) void k_zero(int* deg) {
    int i = blockIdx.x * 256 + threadIdx.x;
    if (i < NN) deg[i] = 0;
}

__global__ __launch_bounds__(256) void k_deg_count(const int* __restrict__ ei, int* deg) {
    int e = blockIdx.x * 256 + threadIdx.x;
    if (e < EE) atomic_add_i32(&deg[ei[EE + e]], 1);
}

__global__ __launch_bounds__(256) void k_dinv(const int* __restrict__ deg, float* dinv) {
    int i = blockIdx.x * 256 + threadIdx.x;
    if (i < NN) dinv[i] = rsqrtf((float)(deg[i] + 1));
}

__global__ __launch_bounds__(256) void k_scan1(const int* __restrict__ deg,
                                               int* __restrict__ rp, int* __restrict__ bsum) {
    __shared__ int sh[256];
    const int t = threadIdx.x;
    const int base = blockIdx.x * 1024 + t * 4;
    int v0 = (base + 0 < NN) ? deg[base + 0] : 0;
    int v1 = (base + 1 < NN) ? deg[base + 1] : 0;
    int v2 = (base + 2 < NN) ? deg[base + 2] : 0;
    int v3 = (base + 3 < NN) ? deg[base + 3] : 0;
    int s = v0 + v1 + v2 + v3;
    sh[t] = s;
    __syncthreads();
    for (int off = 1; off < 256; off <<= 1) {
        int x = (t >= off) ? sh[t - off] : 0;
        __syncthreads();
        sh[t] += x;
        __syncthreads();
    }
    int excl = sh[t] - s;
    if (t == 255) bsum[blockIdx.x] = sh[255];
    if (base + 0 < NN) rp[base + 0] = excl;
    if (base + 1 < NN) rp[base + 1] = excl + v0;
    if (base + 2 < NN) rp[base + 2] = excl + v0 + v1;
    if (base + 3 < NN) rp[base + 3] = excl + v0 + v1 + v2;
}

__global__ __launch_bounds__(128) void k_scan2(int* __restrict__ bsum, int* __restrict__ boff) {
    __shared__ int sh[128];
    const int t = threadIdx.x;
    int v = (t < NB1) ? bsum[t] : 0;
    sh[t] = v;
    __syncthreads();
    for (int off = 1; off < 128; off <<= 1) {
        int x = (t >= off) ? sh[t - off] : 0;
        __syncthreads();
        sh[t] += x;
        __syncthreads();
    }
    if (t < NB1) boff[t] = sh[t] - v;
}

// finalize rp and seed cursor = rp
__global__ __launch_bounds__(256) void k_scan3(int* __restrict__ rp, const int* __restrict__ boff,
                                               int* __restrict__ cursor) {
    int i = blockIdx.x * 256 + threadIdx.x;
    if (i < NN) {
        int v = rp[i] + boff[i >> 10];
        rp[i] = v;
        cursor[i] = v;
    }
}

__global__ __launch_bounds__(256) void k_fill(const int* __restrict__ ei,
                                              const float* __restrict__ dinv,
                                              int* __restrict__ cursor,
                                              int2* __restrict__ csr) {
    int e = blockIdx.x * 256 + threadIdx.x;
    if (e >= EE) return;
    int s = ei[e];
    int d = ei[EE + e];
    float w = dinv[s] * dinv[d];
    int pos = atomic_add_i32(&cursor[d], 1);
    csr[pos] = make_int2(s, __float_as_int(w));
}

// h1 = x @ W1 via f16 MFMA. Block: 64 rows, 4 waves (each 16 rows x 64 cols).
__global__ __launch_bounds__(256) void k_gemm1(const float* __restrict__ x,
                                               const _Float16* __restrict__ w1t,
                                               _Float16* __restrict__ h1) {
    __shared__ _Float16 As[64 * IN_F];   // 16 KB, swizzled rows of 256B
    __shared__ _Float16 Bs[64 * IN_F];   // W1^T, 16 KB
    const int tid = threadIdx.x;
    const size_t r0 = (size_t)blockIdx.x * 64;

    #pragma unroll
    for (int i = 0; i < 8; ++i) {            // A: 2048 float4 chunks
        int f = i * 256 + tid;
        int row = f >> 5;
        int k4 = (f & 31) * 4;
        size_t gr = r0 + row; if (gr >= NN) gr = NN - 1;
        float4 v = *(const float4*)&x[gr * IN_F + k4];
        _Float16 h[4] = {(_Float16)v.x, (_Float16)v.y, (_Float16)v.z, (_Float16)v.w};
        *(uint2*)((char*)As + SWZ(row * 256 + k4 * 2, row)) = *(uint2*)h;
    }
    #pragma unroll
    for (int i = 0; i < 4; ++i) {            // B: 1024 16B chunks
        int c = i * 256 + tid;
        int col = c >> 4;
        int k8 = (c & 15) * 8;
        uint4 v = *(const uint4*)&w1t[col * IN_F + k8];
        *(uint4*)((char*)Bs + SWZ(col * 256 + k8 * 2, col)) = v;
    }
    __syncthreads();

    const int w = tid >> 6, l = tid & 63;
    const int lr = l & 15, lg = l >> 4;
    const int R0 = w * 16;
    f32x4 acc[4] = {};
    #pragma unroll
    for (int kk = 0; kk < 4; ++kk) {
        const int kbyte = (kk * 32 + lg * 8) * 2;
        const int arow = R0 + lr;
        half8 a = *(const half8*)((const char*)As + SWZ(arow * 256 + kbyte, arow));
        #pragma unroll
        for (int t = 0; t < 4; ++t) {
            const int bcol = t * 16 + lr;
            half8 b = *(const half8*)((const char*)Bs + SWZ(bcol * 256 + kbyte, bcol));
            acc[t] = __builtin_amdgcn_mfma_f32_16x16x32_f16(a, b, acc[t], 0, 0, 0);
        }
    }
    #pragma unroll
    for (int t = 0; t < 4; ++t)
        #pragma unroll
        for (int r = 0; r < 4; ++r) {
            size_t row = r0 + R0 + lg * 4 + r;
            if (row < NN) h1[row * HID_F + t * 16 + lr] = (_Float16)acc[t][r];
        }
}

// agg1: 1 wave per node; two half-waves process 2 edges concurrently; 2x unroll.
// h_relu[v] = relu( h1[v]*dinv^2 + sum w*h1[src] + b1 )   (fp16 out)
__global__ __launch_bounds__(256) void k_agg1(const _Float16* __restrict__ h1,
                                              const float* __restrict__ dinv,
                                              const int* __restrict__ rp,
                                              const int* __restrict__ deg,
                                              const int2* __restrict__ csr,
                                              const float* __restrict__ b1,
                                              _Float16* __restrict__ hrelu) {
    const int v = blockIdx.x * 4 + (threadIdx.x >> 6);
    if (v >= NN) return;
    const int lane = threadIdx.x & 63;
    const int g = lane >> 5;     // edge slot within wave
    const int c = lane & 31;     // feature pair
    const float dv = dinv[v];

    float2 acc = {0.f, 0.f};
    if (g == 0) {
        float2 self = unpack_h2(*(const unsigned*)&h1[(size_t)v * HID_F + c * 2]);
        float d2 = dv * dv;
        acc.x = self.x * d2; acc.y = self.y * d2;
    }
    const int e0 = rp[v];
    const int end = e0 + deg[v];
    int t = e0 + g;
    for (; t + 2 < end; t += 4) {
        int2 p0 = csr[t];
        int2 p1 = csr[t + 2];
        unsigned u0 = *(const unsigned*)&h1[(size_t)p0.x * HID_F + c * 2];
        unsigned u1 = *(const unsigned*)&h1[(size_t)p1.x * HID_F + c * 2];
        float w0 = __int_as_float(p0.y), w1 = __int_as_float(p1.y);
        float2 x0 = unpack_h2(u0), x1 = unpack_h2(u1);
        acc.x += w0 * x0.x + w1 * x1.x;
        acc.y += w0 * x0.y + w1 * x1.y;
    }
    if (t < end) {
        int2 p = csr[t];
        float2 xv = unpack_h2(*(const unsigned*)&h1[(size_t)p.x * HID_F + c * 2]);
        float w = __int_as_float(p.y);
        acc.x += w * xv.x; acc.y += w * xv.y;
    }
    acc.x += __shfl_xor(acc.x, 32);
    acc.y += __shfl_xor(acc.y, 32);
    if (g == 0) {
        float rx = fmaxf(acc.x + b1[c * 2], 0.f);
        float ry = fmaxf(acc.y + b1[c * 2 + 1], 0.f);
        union { unsigned u; _Float16 h[2]; } o;
        o.h[0] = (_Float16)rx; o.h[1] = (_Float16)ry;
        *(unsigned*)&hrelu[(size_t)v * HID_F + c * 2] = o.u;
    }
}

// h2 = h_relu @ W2 via f16 MFMA. Block: 64 rows, 4 waves (each 16 rows x 48 cols).
__global__ __launch_bounds__(256) void k_gemm2(const _Float16* __restrict__ hr,
                                               const _Float16* __restrict__ w2t,
                                               _Float16* __restrict__ h2) {
    __shared__ _Float16 As[64 * HID_F];  // 8 KB, rows of 128B swizzled
    __shared__ _Float16 Bs[48 * HID_F];  // 6 KB
    const int tid = threadIdx.x;
    const size_t r0 = (size_t)blockIdx.x * 64;

    #pragma unroll
    for (int i = 0; i < 2; ++i) {            // A: 512 16B chunks
        int c = i * 256 + tid;
        int row = c >> 3;
        int k8 = (c & 7) * 8;
        size_t gr = r0 + row; if (gr >= NN) gr = NN - 1;
        uint4 v = *(const uint4*)&hr[gr * HID_F + k8];
        *(uint4*)((char*)As + SWZ(row * 128 + k8 * 2, row)) = v;
    }
    for (int c = tid; c < 384; c += 256) {   // B: 384 16B chunks
        int col = c >> 3;
        int k8 = (c & 7) * 8;
        uint4 v = *(const uint4*)&w2t[col * HID_F + k8];
        *(uint4*)((char*)Bs + SWZ(col * 128 + k8 * 2, col)) = v;
    }
    __syncthreads();

    const int w = tid >> 6, l = tid & 63;
    const int lr = l & 15, lg = l >> 4;
    const int R0 = w * 16;
    f32x4 acc[3] = {};
    #pragma unroll
    for (int kk = 0; kk < 2; ++kk) {
        const int kbyte = (kk * 32 + lg * 8) * 2;
        const int arow = R0 + lr;
        half8 a = *(const half8*)((const char*)As + SWZ(arow * 128 + kbyte, arow));
        #pragma unroll
        for (int t = 0; t < 3; ++t) {
            const int bcol = t * 16 + lr;
            half8 b = *(const half8*)((const char*)Bs + SWZ(bcol * 128 + kbyte, bcol));
            acc[t] = __builtin_amdgcn_mfma_f32_16x16x32_f16(a, b, acc[t], 0, 0, 0);
        }
    }
    #pragma unroll
    for (int t = 0; t < 3; ++t) {
        const int col = t * 16 + lr;
        if (col >= OUT_F) continue;
        #pragma unroll
        for (int r = 0; r < 4; ++r) {
            size_t row = r0 + R0 + lg * 4 + r;
            if (row < NN) h2[row * OUT_F + col] = (_Float16)acc[t][r];
        }
    }
}

// agg2: 1 wave per node; two half-waves x 20 active lane-pairs (40 feats).
// out[v] = h2[v]*dinv^2 + sum w*h2[src] + b2   (fp32 out)
__global__ __launch_bounds__(256) void k_agg2(const _Float16* __restrict__ h2,
                                              const float* __restrict__ dinv,
                                              const int* __restrict__ rp,
                                              const int* __restrict__ deg,
                                              const int2* __restrict__ csr,
                                              const float* __restrict__ b2,
                                              float* __restrict__ out) {
    const int v = blockIdx.x * 4 + (threadIdx.x >> 6);
    if (v >= NN) return;
    const int lane = threadIdx.x & 63;
    const int g = lane >> 5;
    const int c = lane & 31;
    const int cc = (c < 20) ? c : 0;   // clamp for safe addresses
    const float dv = dinv[v];

    float2 acc = {0.f, 0.f};
    if (g == 0) {
        float2 self = unpack_h2(*(const unsigned*)&h2[(size_t)v * OUT_F + cc * 2]);
        float d2 = dv * dv;
        acc.x = self.x * d2; acc.y = self.y * d2;
    }
    const int e0 = rp[v];
    const int end = e0 + deg[v];
    int t = e0 + g;
    for (; t + 2 < end; t += 4) {
        int2 p0 = csr[t];
        int2 p1 = csr[t + 2];
        unsigned u0 = *(const unsigned*)&h2[(size_t)p0.x * OUT_F + cc * 2];
        unsigned u1 = *(const unsigned*)&h2[(size_t)p1.x * OUT_F + cc * 2];
        float w0 = __int_as_float(p0.y), w1 = __int_as_float(p1.y);
        float2 x0 = unpack_h2(u0), x1 = unpack_h2(u1);
        acc.x += w0 * x0.x + w1 * x1.x;
        acc.y += w0 * x0.y + w1 * x1.y;
    }
    if (t < end) {
        int2 p = csr[t];
        float2 xv = unpack_h2(*(const unsigned*)&h2[(size_t)p.x * OUT_F + cc * 2]);
        float w = __int_as_float(p.y);
        acc.x += w * xv.x; acc.y += w * xv.y;
    }
    acc.x += __shfl_xor(acc.x, 32);
    acc.y += __shfl_xor(acc.y, 32);
    if (g == 0 && c < 20) {
        float2 o = {acc.x + b2[c * 2], acc.y + b2[c * 2 + 1]};
        *(float2*)&out[(size_t)v * OUT_F + c * 2] = o;
    }
}

extern "C" void kernel_launch(void* const* d_in, const int* in_sizes, int n_in,
                              void* d_out, int out_size, void* d_ws, size_t ws_size,
                              hipStream_t stream) {
    const float* x  = (const float*)d_in[0];
    const int*   ei = (const int*)d_in[1];
    const float* W1 = (const float*)d_in[2];
    const float* b1 = (const float*)d_in[3];
    const float* W2 = (const float*)d_in[4];
    const float* b2 = (const float*)d_in[5];
    float* out = (float*)d_out;

    char* p = (char*)d_ws;
    float*     dinv  = (float*)p;     p += (size_t)NN * 4;
    int*       deg   = (int*)p;       p += (size_t)NN * 4;
    int*       rp    = (int*)p;       p += (size_t)NN * 4;
    int*       cursor= (int*)p;       p += (size_t)NN * 4;
    int*       bsum  = (int*)p;       p += 128 * 4;
    int*       boff  = (int*)p;       p += 128 * 4;
    _Float16*  w1t   = (_Float16*)p;  p += (size_t)IN_F * HID_F * 2;
    _Float16*  w2t   = (_Float16*)p;  p += (size_t)48 * HID_F * 2;
    int2*      csr   = (int2*)p;      p += (size_t)EE * 8;
    _Float16*  h1    = (_Float16*)p;  p += (size_t)NN * HID_F * 2;   // reused as h2
    _Float16*  hrelu = (_Float16*)p;  p += (size_t)NN * HID_F * 2;
    _Float16*  h2    = h1;

    const int gemm_blocks = (NN + 63) / 64;

    k_prep     <<<44, 256, 0, stream>>>(W1, W2, w1t, w2t);
    k_zero     <<<(NN + 255) / 256, 256, 0, stream>>>(deg);
    k_deg_count<<<(EE + 255) / 256, 256, 0, stream>>>(ei, deg);
    k_dinv     <<<(NN + 255) / 256, 256, 0, stream>>>(deg, dinv);
    k_scan1    <<<NB1, 256, 0, stream>>>(deg, rp, bsum);
    k_scan2    <<<1, 128, 0, stream>>>(bsum, boff);
    k_scan3    <<<(NN + 255) / 256, 256, 0, stream>>>(rp, boff, cursor);
    k_fill     <<<(EE + 255) / 256, 256, 0, stream>>>(ei, dinv, cursor, csr);
    k_gemm1    <<<gemm_blocks, 256, 0, stream>>>(x, w1t, h1);
    k_agg1     <<<(NN + 3) / 4, 256, 0, stream>>>(h1, dinv, rp, deg, csr, b1, hrelu);
    k_gemm2    <<<gemm_blocks, 256, 0, stream>>>(hrelu, w2t, h2);
    k_agg2     <<<(NN + 3) / 4, 256, 0, stream>>>(h2, dinv, rp, deg, csr, b2, out);
}

// Round 4
// 182.984 us; speedup vs baseline: 8.5268x; 1.2703x over previous
//
#include <hip/hip_runtime.h>

#define NN 100000
#define EE 1000000
#define IN_F 128
#define HID_F 64
#define OUT_F 40
#define NB1 98   // ceil(NN/1024) for scan

typedef _Float16 half8 __attribute__((ext_vector_type(8)));
typedef _Float16 half4 __attribute__((ext_vector_type(4)));
typedef float f32x4 __attribute__((ext_vector_type(4)));

#define SWZ(b, row) ((b) ^ (((row) & 7) << 4))

static __device__ __forceinline__ int atomic_add_i32(int* p, int v) {
    return __hip_atomic_fetch_add(p, v, __ATOMIC_RELAXED, __HIP_MEMORY_SCOPE_AGENT);
}

// Fused: deg zero + W1 transpose->fp16 + W2 transpose->fp16(48-pad)
__global__ __launch_bounds__(256) void k_prep(const float* __restrict__ W1,
                                              const float* __restrict__ W2,
                                              _Float16* __restrict__ w1t,
                                              _Float16* __restrict__ w2t,
                                              int* __restrict__ deg) {
    int i = blockIdx.x * 256 + threadIdx.x;
    if (i < IN_F * HID_F) {
        int k = i >> 6, n = i & 63;
        w1t[n * IN_F + k] = (_Float16)W1[i];
    }
    if (i < 48 * HID_F) {
        int n = i >> 6, k = i & 63;
        w2t[i] = (_Float16)((n < OUT_F) ? W2[k * OUT_F + n] : 0.f);
    }
    if (i < NN) deg[i] = 0;
}

// slot[e] = running index of edge e within its dst bucket; deg = histogram
__global__ __launch_bounds__(256) void k_deg_slot(const int* __restrict__ ei,
                                                  int* __restrict__ deg,
                                                  int* __restrict__ slot) {
    int e = blockIdx.x * 256 + threadIdx.x;
    if (e < EE) slot[e] = atomic_add_i32(&deg[ei[EE + e]], 1);
}

// per-1024 partial scan + block sums; also dinv = rsqrt(deg+1)
__global__ __launch_bounds__(256) void k_scan1(const int* __restrict__ deg,
                                               int* __restrict__ rp, int* __restrict__ bsum,
                                               float* __restrict__ dinv) {
    __shared__ int sh[256];
    const int t = threadIdx.x;
    const int base = blockIdx.x * 1024 + t * 4;
    int v0 = (base + 0 < NN) ? deg[base + 0] : 0;
    int v1 = (base + 1 < NN) ? deg[base + 1] : 0;
    int v2 = (base + 2 < NN) ? deg[base + 2] : 0;
    int v3 = (base + 3 < NN) ? deg[base + 3] : 0;
    if (base + 0 < NN) dinv[base + 0] = rsqrtf((float)(v0 + 1));
    if (base + 1 < NN) dinv[base + 1] = rsqrtf((float)(v1 + 1));
    if (base + 2 < NN) dinv[base + 2] = rsqrtf((float)(v2 + 1));
    if (base + 3 < NN) dinv[base + 3] = rsqrtf((float)(v3 + 1));
    int s = v0 + v1 + v2 + v3;
    sh[t] = s;
    __syncthreads();
    for (int off = 1; off < 256; off <<= 1) {
        int x = (t >= off) ? sh[t - off] : 0;
        __syncthreads();
        sh[t] += x;
        __syncthreads();
    }
    int excl = sh[t] - s;
    if (t == 255) bsum[blockIdx.x] = sh[255];
    if (base + 0 < NN) rp[base + 0] = excl;
    if (base + 1 < NN) rp[base + 1] = excl + v0;
    if (base + 2 < NN) rp[base + 2] = excl + v0 + v1;
    if (base + 3 < NN) rp[base + 3] = excl + v0 + v1 + v2;
}

__global__ __launch_bounds__(128) void k_scan2(int* __restrict__ bsum, int* __restrict__ boff) {
    __shared__ int sh[128];
    const int t = threadIdx.x;
    int v = (t < NB1) ? bsum[t] : 0;
    sh[t] = v;
    __syncthreads();
    for (int off = 1; off < 128; off <<= 1) {
        int x = (t >= off) ? sh[t - off] : 0;
        __syncthreads();
        sh[t] += x;
        __syncthreads();
    }
    if (t < NB1) boff[t] = sh[t] - v;
}

__global__ __launch_bounds__(256) void k_scan3(int* __restrict__ rp, const int* __restrict__ boff) {
    int i = blockIdx.x * 256 + threadIdx.x;
    if (i < NN) rp[i] += boff[i >> 10];
    if (i == 0) rp[NN] = EE;
}

// csr[rp[d] + slot[e]] = src   (no atomics)
__global__ __launch_bounds__(256) void k_fill(const int* __restrict__ ei,
                                              const int* __restrict__ rp,
                                              const int* __restrict__ slot,
                                              int* __restrict__ csr) {
    int e = blockIdx.x * 256 + threadIdx.x;
    if (e >= EE) return;
    int s = ei[e];
    int d = ei[EE + e];
    csr[rp[d] + slot[e]] = s;
}

// h1s = dinv * (x @ W1), fp16. Block: 64 rows, 4 waves.
__global__ __launch_bounds__(256) void k_gemm1(const float* __restrict__ x,
                                               const _Float16* __restrict__ w1t,
                                               const float* __restrict__ dinv,
                                               _Float16* __restrict__ h1s) {
    __shared__ _Float16 As[64 * IN_F];
    __shared__ _Float16 Bs[64 * IN_F];
    const int tid = threadIdx.x;
    const size_t r0 = (size_t)blockIdx.x * 64;

    #pragma unroll
    for (int i = 0; i < 8; ++i) {
        int f = i * 256 + tid;
        int row = f >> 5;
        int k4 = (f & 31) * 4;
        size_t gr = r0 + row; if (gr >= NN) gr = NN - 1;
        float4 v = *(const float4*)&x[gr * IN_F + k4];
        _Float16 h[4] = {(_Float16)v.x, (_Float16)v.y, (_Float16)v.z, (_Float16)v.w};
        *(uint2*)((char*)As + SWZ(row * 256 + k4 * 2, row)) = *(uint2*)h;
    }
    #pragma unroll
    for (int i = 0; i < 4; ++i) {
        int c = i * 256 + tid;
        int col = c >> 4;
        int k8 = (c & 15) * 8;
        uint4 v = *(const uint4*)&w1t[col * IN_F + k8];
        *(uint4*)((char*)Bs + SWZ(col * 256 + k8 * 2, col)) = v;
    }
    __syncthreads();

    const int w = tid >> 6, l = tid & 63;
    const int lr = l & 15, lg = l >> 4;
    const int R0 = w * 16;
    f32x4 acc[4] = {};
    #pragma unroll
    for (int kk = 0; kk < 4; ++kk) {
        const int kbyte = (kk * 32 + lg * 8) * 2;
        const int arow = R0 + lr;
        half8 a = *(const half8*)((const char*)As + SWZ(arow * 256 + kbyte, arow));
        #pragma unroll
        for (int t = 0; t < 4; ++t) {
            const int bcol = t * 16 + lr;
            half8 b = *(const half8*)((const char*)Bs + SWZ(bcol * 256 + kbyte, bcol));
            acc[t] = __builtin_amdgcn_mfma_f32_16x16x32_f16(a, b, acc[t], 0, 0, 0);
        }
    }
    #pragma unroll
    for (int r = 0; r < 4; ++r) {
        size_t row = r0 + R0 + lg * 4 + r;
        if (row < NN) {
            float dv = dinv[row];
            #pragma unroll
            for (int t = 0; t < 4; ++t)
                h1s[row * HID_F + t * 16 + lr] = (_Float16)(dv * acc[t][r]);
        }
    }
}

// agg1: 1 wave/node, 4 quarter-waves x 16 lanes (half4 each = 128B row), 2x unroll.
// hrelu[v] = relu( dinv[v] * (sum h1s[src] + h1s[v]) + b1 )
__global__ __launch_bounds__(256) void k_agg1(const _Float16* __restrict__ h1s,
                                              const float* __restrict__ dinv,
                                              const int* __restrict__ rp,
                                              const int* __restrict__ csr,
                                              const float* __restrict__ b1,
                                              _Float16* __restrict__ hrelu) {
    const int v = blockIdx.x * 4 + (threadIdx.x >> 6);
    if (v >= NN) return;
    const int lane = threadIdx.x & 63;
    const int g = lane >> 4;
    const int c = lane & 15;
    const size_t base = (size_t)v << 6;

    half4 acc16 = {};
    if (g == 0) acc16 = *(const half4*)&h1s[base + c * 4];   // self
    int t = rp[v] + g;
    const int end = rp[v + 1];
    for (; t + 4 < end; t += 8) {
        int s0 = csr[t];
        int s1 = csr[t + 4];
        half4 a = *(const half4*)&h1s[((size_t)s0 << 6) + c * 4];
        half4 b = *(const half4*)&h1s[((size_t)s1 << 6) + c * 4];
        acc16 += a;
        acc16 += b;
    }
    if (t < end)
        acc16 += *(const half4*)&h1s[((size_t)csr[t] << 6) + c * 4];

    float a0 = (float)acc16.x, a1 = (float)acc16.y, a2 = (float)acc16.z, a3 = (float)acc16.w;
    a0 += __shfl_xor(a0, 16); a1 += __shfl_xor(a1, 16); a2 += __shfl_xor(a2, 16); a3 += __shfl_xor(a3, 16);
    a0 += __shfl_xor(a0, 32); a1 += __shfl_xor(a1, 32); a2 += __shfl_xor(a2, 32); a3 += __shfl_xor(a3, 32);
    if (g == 0) {
        const float dv = dinv[v];
        float4 bb = *(const float4*)&b1[c * 4];
        _Float16 o[4];
        o[0] = (_Float16)fmaxf(dv * a0 + bb.x, 0.f);
        o[1] = (_Float16)fmaxf(dv * a1 + bb.y, 0.f);
        o[2] = (_Float16)fmaxf(dv * a2 + bb.z, 0.f);
        o[3] = (_Float16)fmaxf(dv * a3 + bb.w, 0.f);
        *(uint2*)&hrelu[base + c * 4] = *(uint2*)o;
    }
}

// h2s = dinv * (hrelu @ W2), fp16, row stride 64 (cols 40..47 zeroed, 48..63 untouched)
__global__ __launch_bounds__(256) void k_gemm2(const _Float16* __restrict__ hr,
                                               const _Float16* __restrict__ w2t,
                                               const float* __restrict__ dinv,
                                               _Float16* __restrict__ h2s) {
    __shared__ _Float16 As[64 * HID_F];
    __shared__ _Float16 Bs[48 * HID_F];
    const int tid = threadIdx.x;
    const size_t r0 = (size_t)blockIdx.x * 64;

    #pragma unroll
    for (int i = 0; i < 2; ++i) {
        int c = i * 256 + tid;
        int row = c >> 3;
        int k8 = (c & 7) * 8;
        size_t gr = r0 + row; if (gr >= NN) gr = NN - 1;
        uint4 v = *(const uint4*)&hr[gr * HID_F + k8];
        *(uint4*)((char*)As + SWZ(row * 128 + k8 * 2, row)) = v;
    }
    for (int c = tid; c < 384; c += 256) {
        int col = c >> 3;
        int k8 = (c & 7) * 8;
        uint4 v = *(const uint4*)&w2t[col * HID_F + k8];
        *(uint4*)((char*)Bs + SWZ(col * 128 + k8 * 2, col)) = v;
    }
    __syncthreads();

    const int w = tid >> 6, l = tid & 63;
    const int lr = l & 15, lg = l >> 4;
    const int R0 = w * 16;
    f32x4 acc[3] = {};
    #pragma unroll
    for (int kk = 0; kk < 2; ++kk) {
        const int kbyte = (kk * 32 + lg * 8) * 2;
        const int arow = R0 + lr;
        half8 a = *(const half8*)((const char*)As + SWZ(arow * 128 + kbyte, arow));
        #pragma unroll
        for (int t = 0; t < 3; ++t) {
            const int bcol = t * 16 + lr;
            half8 b = *(const half8*)((const char*)Bs + SWZ(bcol * 128 + kbyte, bcol));
            acc[t] = __builtin_amdgcn_mfma_f32_16x16x32_f16(a, b, acc[t], 0, 0, 0);
        }
    }
    #pragma unroll
    for (int r = 0; r < 4; ++r) {
        size_t row = r0 + R0 + lg * 4 + r;
        if (row < NN) {
            float dv = dinv[row];
            #pragma unroll
            for (int t = 0; t < 3; ++t) {
                int col = t * 16 + lr;
                float val = (col < OUT_F) ? dv * acc[t][r] : 0.f;
                h2s[row * 64 + col] = (_Float16)val;
            }
        }
    }
}

// agg2: out[v] = dinv[v] * (sum h2s[src] + h2s[v]) + b2   (fp32 out, 40 feats)
__global__ __launch_bounds__(256) void k_agg2(const _Float16* __restrict__ h2s,
                                              const float* __restrict__ dinv,
                                              const int* __restrict__ rp,
                                              const int* __restrict__ csr,
                                              const float* __restrict__ b2,
                                              float* __restrict__ out) {
    const int v = blockIdx.x * 4 + (threadIdx.x >> 6);
    if (v >= NN) return;
    const int lane = threadIdx.x & 63;
    const int g = lane >> 4;
    const int c = lane & 15;
    const size_t base = (size_t)v << 6;

    half4 acc16 = {};
    if (g == 0) acc16 = *(const half4*)&h2s[base + c * 4];
    int t = rp[v] + g;
    const int end = rp[v + 1];
    for (; t + 4 < end; t += 8) {
        int s0 = csr[t];
        int s1 = csr[t + 4];
        half4 a = *(const half4*)&h2s[((size_t)s0 << 6) + c * 4];
        half4 b = *(const half4*)&h2s[((size_t)s1 << 6) + c * 4];
        acc16 += a;
        acc16 += b;
    }
    if (t < end)
        acc16 += *(const half4*)&h2s[((size_t)csr[t] << 6) + c * 4];

    float a0 = (float)acc16.x, a1 = (float)acc16.y, a2 = (float)acc16.z, a3 = (float)acc16.w;
    a0 += __shfl_xor(a0, 16); a1 += __shfl_xor(a1, 16); a2 += __shfl_xor(a2, 16); a3 += __shfl_xor(a3, 16);
    a0 += __shfl_xor(a0, 32); a1 += __shfl_xor(a1, 32); a2 += __shfl_xor(a2, 32); a3 += __shfl_xor(a3, 32);
    if (g == 0 && c < 10) {
        const float dv = dinv[v];
        float4 bb = *(const float4*)&b2[c * 4];
        float4 o = {dv * a0 + bb.x, dv * a1 + bb.y, dv * a2 + bb.z, dv * a3 + bb.w};
        *(float4*)&out[(size_t)v * OUT_F + c * 4] = o;
    }
}

extern "C" void kernel_launch(void* const* d_in, const int* in_sizes, int n_in,
                              void* d_out, int out_size, void* d_ws, size_t ws_size,
                              hipStream_t stream) {
    const float* x  = (const float*)d_in[0];
    const int*   ei = (const int*)d_in[1];
    const float* W1 = (const float*)d_in[2];
    const float* b1 = (const float*)d_in[3];
    const float* W2 = (const float*)d_in[4];
    const float* b2 = (const float*)d_in[5];
    float* out = (float*)d_out;

    char* p = (char*)d_ws;
    float*     dinv  = (float*)p;     p += (size_t)NN * 4;
    int*       deg   = (int*)p;       p += (size_t)NN * 4;
    int*       rp    = (int*)p;       p += (size_t)(NN + 1) * 4;
    int*       slot  = (int*)p;       p += (size_t)EE * 4;
    int*       bsum  = (int*)p;       p += 128 * 4;
    int*       boff  = (int*)p;       p += 128 * 4;
    _Float16*  w1t   = (_Float16*)p;  p += (size_t)IN_F * HID_F * 2;
    _Float16*  w2t   = (_Float16*)p;  p += (size_t)48 * HID_F * 2;
    int*       csr   = (int*)p;       p += (size_t)EE * 4;
    _Float16*  h1s   = (_Float16*)p;  p += (size_t)NN * HID_F * 2;   // reused as h2s
    _Float16*  hrelu = (_Float16*)p;  p += (size_t)NN * HID_F * 2;
    _Float16*  h2s   = h1s;

    const int gemm_blocks = (NN + 63) / 64;

    k_prep    <<<(NN + 255) / 256, 256, 0, stream>>>(W1, W2, w1t, w2t, deg);
    k_deg_slot<<<(EE + 255) / 256, 256, 0, stream>>>(ei, deg, slot);
    k_scan1   <<<NB1, 256, 0, stream>>>(deg, rp, bsum, dinv);
    k_scan2   <<<1, 128, 0, stream>>>(bsum, boff);
    k_scan3   <<<(NN + 255) / 256, 256, 0, stream>>>(rp, boff);
    k_fill    <<<(EE + 255) / 256, 256, 0, stream>>>(ei, rp, slot, csr);
    k_gemm1   <<<gemm_blocks, 256, 0, stream>>>(x, w1t, dinv, h1s);
    k_agg1    <<<(NN + 3) / 4, 256, 0, stream>>>(h1s, dinv, rp, csr, b1, hrelu);
    k_gemm2   <<<gemm_blocks, 256, 0, stream>>>(hrelu, w2t, dinv, h2s);
    k_agg2    <<<(NN + 3) / 4, 256, 0, stream>>>(h2s, dinv, rp, csr, b2, out);
}